// Round 22
// baseline (173.424 us; speedup 1.0000x reference)
//
#include <hip/hip_runtime.h>
#include <hip/hip_bf16.h>

#define B_ 4
#define N_ 10000
#define E_ 160000
#define D_ 128
#define H_ 4
#define HID_ 128
#define DK_ 32
#define DE_ 16
#define PGRID 2048
#define QKV_BLKS 625
#define FILM_BLKS 512
#define HIST_BLKS 625   // ceil(E/256)

typedef __attribute__((ext_vector_type(8))) short short8v;
typedef __attribute__((ext_vector_type(4))) short short4v;
typedef __attribute__((ext_vector_type(4))) float f32x4;
typedef __attribute__((ext_vector_type(2))) float f32x2;

// fp32 -> bf16 bits, round-to-nearest-even
__device__ __forceinline__ short bfb(float f) {
  union { float f; unsigned u; } c; c.f = f;
  unsigned u = c.u + 0x7FFFu + ((c.u >> 16) & 1u);
  return (short)(u >> 16);
}
// bf16 bits -> fp32
__device__ __forceinline__ float b2f(unsigned short u) {
  union { unsigned u; float f; } c; c.u = ((unsigned)u) << 16;
  return c.f;
}

// fp32 -> fp8 e4m3 (OCP on gfx950)
__device__ __forceinline__ unsigned char f2fp8(float f) {
  int r = __builtin_amdgcn_cvt_pk_fp8_f32(f, f, 0, false);
  return (unsigned char)(r & 0xff);
}
// dword of 4 fp8 -> 2+2 fp32
__device__ __forceinline__ f32x2 fp8lo(unsigned u) {
  return __builtin_amdgcn_cvt_pk_f32_fp8((int)u, false);
}
__device__ __forceinline__ f32x2 fp8hi(unsigned u) {
  return __builtin_amdgcn_cvt_pk_f32_fp8((int)u, true);
}

// ---------------------------------------------------------------------------
// P0: W^T bf16 prep. wt[m][n][k] = bf16(W_m[k*128+n]),  m: 0=q 1=k 2=v 3=o
// ---------------------------------------------------------------------------
__global__ __launch_bounds__(256) void wt_prep(
    const float* __restrict__ Wq, const float* __restrict__ Wk,
    const float* __restrict__ Wv, const float* __restrict__ Wo,
    short* __restrict__ wt) {
  const float* Ws[4] = {Wq, Wk, Wv, Wo};
  const int i = blockIdx.x * 256 + threadIdx.x;   // 0..65535
  const int m = i >> 14;
  const int k = (i >> 7) & 127;
  const int n = i & 127;
  wt[(size_t)m * 16384 + n * 128 + k] = bfb(Ws[m][k * 128 + n]);
}

// ---------------------------------------------------------------------------
// PHASE 1: co-scheduled qkv + film + hist (mutually independent,
// individually latency-bound at 22-35% occupancy -> overlap them).
// blocks [0, QKV_BLKS): QKV via MFMA, 4 independent 16-row wave-tiles.
// blocks [QKV_BLKS, +FILM_BLKS): FiLM fp8 precompute (original edge order).
// blocks [.., +HIST_BLKS): dst histogram.
// ---------------------------------------------------------------------------
__global__ __launch_bounds__(256) void phase1(
    const float* __restrict__ x, const short* __restrict__ wt,
    const float* __restrict__ bq, const float* __restrict__ bk,
    const float* __restrict__ bv,
    unsigned short* __restrict__ Qb, unsigned char* __restrict__ kv8,
    const float* __restrict__ ea, const float* __restrict__ Wf,
    const float* __restrict__ bf, unsigned char* __restrict__ film8,
    const int* __restrict__ ei, int* __restrict__ cnt) {
  const int blk = blockIdx.x;

  if (blk < QKV_BLKS) {
    // ---------------- QKV (4 wave-tiles per block) ----------------
    __shared__ short xs[4][16][136];
    const int wave = threadIdx.x >> 6;
    const int lane = threadIdx.x & 63;
    const int ln15 = lane & 15;
    const int g    = lane >> 4;
    const long rowBase = ((long)blk * 4 + wave) * 16;

    for (int i = lane; i < 16 * 32; i += 64) {
      const int r  = i >> 5;
      const int c4 = (i & 31) * 4;
      const float4 v = *(const float4*)(x + (rowBase + r) * 128 + c4);
      short4v sv; sv.x = bfb(v.x); sv.y = bfb(v.y); sv.z = bfb(v.z); sv.w = bfb(v.w);
      *(short4v*)&xs[wave][r][c4] = sv;
    }
    __syncthreads();   // branch is uniform per block -> safe

    short8v af[4];
#pragma unroll
    for (int kk = 0; kk < 4; ++kk)
      af[kk] = *(const short8v*)&xs[wave][ln15][kk * 32 + g * 8];

    const float* bs[3] = {bq, bk, bv};

    int bbv[4], nnv[4];
#pragma unroll
    for (int r = 0; r < 4; ++r) {
      const long row = rowBase + g * 4 + r;
      bbv[r] = (int)(row / N_);
      nnv[r] = (int)(row - (long)bbv[r] * N_);
    }

#pragma unroll
    for (int m = 0; m < 3; ++m) {
      const short* Wt = wt + (size_t)m * 16384;
      f32x4 acc[8];
#pragma unroll
      for (int cb = 0; cb < 8; ++cb) acc[cb] = (f32x4){0.f, 0.f, 0.f, 0.f};

#pragma unroll
      for (int kk = 0; kk < 4; ++kk) {
#pragma unroll
        for (int cb = 0; cb < 8; ++cb) {
          const short8v bfr =
              *(const short8v*)(Wt + (cb * 16 + ln15) * 128 + kk * 32 + g * 8);
          acc[cb] = __builtin_amdgcn_mfma_f32_16x16x32_bf16(af[kk], bfr, acc[cb], 0, 0, 0);
        }
      }

      const float* bias = bs[m];
#pragma unroll
      for (int cb = 0; cb < 8; ++cb) {
        const int col = cb * 16 + ln15;
        const float bv_ = bias[col];
#pragma unroll
        for (int r = 0; r < 4; ++r) {
          const float val = acc[cb][r] + bv_;
          if (m == 0) {
            const long row = rowBase + g * 4 + r;
            Qb[row * 128 + col] = (unsigned short)bfb(val);
          } else {
            kv8[(((size_t)nnv[r] * 4 + bbv[r]) << 8) + (m - 1) * 128 + col] = f2fp8(val);
          }
        }
      }
    }
  } else if (blk < QKV_BLKS + FILM_BLKS) {
    // ---------------- FiLM fp8 precompute ----------------
    const int fb   = blk - QKV_BLKS;
    const int lane = threadIdx.x & 63;
    const int wave = threadIdx.x >> 6;
    const int c0 = lane * 4;

    float4 w[16];
#pragma unroll
    for (int j = 0; j < 16; ++j) w[j] = *(const float4*)(Wf + j * 256 + c0);
    const float4 bias = *(const float4*)(bf + c0);

    for (int i = fb * 4 + wave; i < E_; i += FILM_BLKS * 4) {
      const float* ep = ea + (size_t)i * 16;
      const float4 a0 = *(const float4*)ep;
      const float4 a1 = *(const float4*)(ep + 4);
      const float4 a2 = *(const float4*)(ep + 8);
      const float4 a3 = *(const float4*)(ep + 12);
      const float ev[16] = {a0.x,a0.y,a0.z,a0.w, a1.x,a1.y,a1.z,a1.w,
                            a2.x,a2.y,a2.z,a2.w, a3.x,a3.y,a3.z,a3.w};
      float ox = bias.x, oy = bias.y, oz = bias.z, ow = bias.w;
#pragma unroll
      for (int j = 0; j < 16; ++j) {
        ox = fmaf(ev[j], w[j].x, ox);
        oy = fmaf(ev[j], w[j].y, oy);
        oz = fmaf(ev[j], w[j].z, oz);
        ow = fmaf(ev[j], w[j].w, ow);
      }
      int r = __builtin_amdgcn_cvt_pk_fp8_f32(ox, oy, 0, false);
      r = __builtin_amdgcn_cvt_pk_fp8_f32(oz, ow, r, true);
      ((int*)(film8 + (size_t)i * 256))[lane] = r;
    }
  } else {
    // ---------------- dst histogram ----------------
    const int e = (blk - QKV_BLKS - FILM_BLKS) * 256 + threadIdx.x;
    if (e < E_) atomicAdd(&cnt[ei[E_ + e]], 1);
  }
}

// ---------------------------------------------------------------------------
// CSR scan
// ---------------------------------------------------------------------------
__global__ __launch_bounds__(1024) void csr_scan(const int* __restrict__ cnt,
                                                 int* __restrict__ rowptr,
                                                 int* __restrict__ fill) {
  __shared__ int part[1024];
  const int t = threadIdx.x;
  int local[10];
  int sum = 0;
#pragma unroll
  for (int i = 0; i < 10; ++i) {
    const int idx = t * 10 + i;
    local[i] = sum;
    sum += (idx < N_) ? cnt[idx] : 0;
  }
  part[t] = sum;
  __syncthreads();
  for (int off = 1; off < 1024; off <<= 1) {
    const int v = (t >= off) ? part[t - off] : 0;
    __syncthreads();
    part[t] += v;
    __syncthreads();
  }
  const int excl = (t == 0) ? 0 : part[t - 1];
#pragma unroll
  for (int i = 0; i < 10; ++i) {
    const int idx = t * 10 + i;
    if (idx <= N_) {
      const int o = excl + local[i];
      rowptr[idx] = o;
      if (idx < N_) fill[idx] = o;
    }
  }
}

// scatter: CSR-ordered src + original-edge-id map (no edge_attr copy)
__global__ __launch_bounds__(256) void csr_scatter(
    const int* __restrict__ ei, int* __restrict__ fill,
    int* __restrict__ esrc, int* __restrict__ eord) {
  const int e = blockIdx.x * 256 + threadIdx.x;
  if (e < E_) {
    const int dst = ei[E_ + e];
    const int pos = atomicAdd(&fill[dst], 1);
    esrc[pos] = ei[e];
    eord[pos] = e;
  }
}

// ---------------------------------------------------------------------------
// K2: fused logits + softmax + aggregation — ZERO shuffles in the edge loop.
// Persistent: PGRID blocks x 4 waves; wave = node (grid-stride).
// lane = e2*32 + dh*16 + b*4 + h.  film gathered via eord (original edge id).
// ---------------------------------------------------------------------------
__global__ __launch_bounds__(256) void fused_attn(
    const int* __restrict__ rowptr, const int* __restrict__ esrc,
    const int* __restrict__ eord, const unsigned char* __restrict__ film8,
    const unsigned short* __restrict__ Qb,
    const unsigned char* __restrict__ kv8, float* __restrict__ agg) {
  const int wave = threadIdx.x >> 6;
  const int lane = threadIdx.x & 63;
  const int e2 = lane >> 5;
  const int dh = (lane >> 4) & 1;
  const int b  = (lane >> 2) & 3;
  const int h  = lane & 3;
  const int col0 = h * 32 + dh * 16;

  for (int node = blockIdx.x * 4 + wave; node < N_; node += PGRID * 4) {
    const int beg = rowptr[node], end = rowptr[node + 1];

    float q[16];
    {
      const unsigned short* qp = Qb + ((size_t)b * N_ + node) * 128 + col0;
      const short8v t0 = *(const short8v*)qp;
      const short8v t1 = *(const short8v*)(qp + 8);
#pragma unroll
      for (int j = 0; j < 8; ++j) {
        q[j]     = b2f((unsigned short)t0[j]);
        q[8 + j] = b2f((unsigned short)t1[j]);
      }
    }
    float acc[16];
#pragma unroll
    for (int d = 0; d < 16; ++d) acc[d] = 0.f;
    float se = 0.f;

    for (int i0 = beg; i0 < end; i0 += 2) {
      const int ii = i0 + e2;
      const bool valid = ii < end;
      const int ic = valid ? ii : i0;
      const int src = esrc[ic];
      const int de  = eord[ic];
      const unsigned char* kp = kv8 + ((((size_t)src << 2) + b) << 8) + col0;
      const unsigned char* fp = film8 + (size_t)de * 256 + col0;
      const uint4 kw = *(const uint4*)kp;
      const uint4 vw = *(const uint4*)(kp + 128);
      const uint4 gw = *(const uint4*)fp;
      const uint4 tw = *(const uint4*)(fp + 128);
      const unsigned ks[4] = {kw.x, kw.y, kw.z, kw.w};
      const unsigned vs[4] = {vw.x, vw.y, vw.z, vw.w};
      const unsigned gs[4] = {gw.x, gw.y, gw.z, gw.w};
      const unsigned ts[4] = {tw.x, tw.y, tw.z, tw.w};

      float pacc[4] = {0.f, 0.f, 0.f, 0.f};
#pragma unroll
      for (int w = 0; w < 4; ++w) {
        const f32x2 k0 = fp8lo(ks[w]), k1 = fp8hi(ks[w]);
        const f32x2 g0 = fp8lo(gs[w]), g1 = fp8hi(gs[w]);
        const f32x2 t0 = fp8lo(ts[w]), t1 = fp8hi(ts[w]);
        float km;
        km = k0.x + fmaf(k0.x, g0.x, t0.x); pacc[w] = fmaf(q[4*w+0], km, pacc[w]);
        km = k0.y + fmaf(k0.y, g0.y, t0.y); pacc[w] = fmaf(q[4*w+1], km, pacc[w]);
        km = k1.x + fmaf(k1.x, g1.x, t1.x); pacc[w] = fmaf(q[4*w+2], km, pacc[w]);
        km = k1.y + fmaf(k1.y, g1.y, t1.y); pacc[w] = fmaf(q[4*w+3], km, pacc[w]);
      }
      float pl = (pacc[0] + pacc[1]) + (pacc[2] + pacc[3]);
      pl += __shfl_xor(pl, 16);   // join dh halves -> full 32-dim logit

      float ex = __expf(pl * 0.17677669529663687f);  // 1/sqrt(32)
      ex = valid ? ex : 0.f;
      se += ex;
#pragma unroll
      for (int w = 0; w < 4; ++w) {
        const f32x2 v0 = fp8lo(vs[w]), v1 = fp8hi(vs[w]);
        acc[4*w+0] = fmaf(ex, v0.x, acc[4*w+0]);
        acc[4*w+1] = fmaf(ex, v0.y, acc[4*w+1]);
        acc[4*w+2] = fmaf(ex, v1.x, acc[4*w+2]);
        acc[4*w+3] = fmaf(ex, v1.y, acc[4*w+3]);
      }
    }

    // join the two e2 slots
#pragma unroll
    for (int d = 0; d < 16; ++d) acc[d] += __shfl_xor(acc[d], 32);
    se += __shfl_xor(se, 32);

    if (e2 == 0) {
      const float inv = (end > beg) ? 1.f / se : 0.f;
      float* ap = agg + ((size_t)b * N_ + node) * 128 + col0;
#pragma unroll
      for (int c = 0; c < 4; ++c) {
        float4 o;
        o.x = acc[c*4+0] * inv; o.y = acc[c*4+1] * inv;
        o.z = acc[c*4+2] * inv; o.w = acc[c*4+3] * inv;
        *(float4*)(ap + c * 4) = o;
      }
    }
  }
}

// ---------------------------------------------------------------------------
// K4: y = agg @ Wo + bo (MFMA); h = x + y; LayerNorm(h) -> out
// ONE WAVE per block, 16 rows/block, grid 2500.
// ---------------------------------------------------------------------------
__global__ __launch_bounds__(64) void out_ln_mfma(
    const float* __restrict__ agg, const short* __restrict__ wto,
    const float* __restrict__ bo, const float* __restrict__ x,
    const float* __restrict__ lng, const float* __restrict__ lnb,
    float* __restrict__ out) {
  __shared__ short as_[16][136];
  const int lane = threadIdx.x;
  const int ln15 = lane & 15;
  const int g    = lane >> 4;
  const long rowBase = (long)blockIdx.x * 16;

  for (int i = lane; i < 16 * 32; i += 64) {
    const int r  = i >> 5;
    const int c4 = (i & 31) * 4;
    const float4 v = *(const float4*)(agg + (rowBase + r) * 128 + c4);
    short4v sv; sv.x = bfb(v.x); sv.y = bfb(v.y); sv.z = bfb(v.z); sv.w = bfb(v.w);
    *(short4v*)&as_[r][c4] = sv;
  }
  __syncthreads();

  short8v af[4];
#pragma unroll
  for (int kk = 0; kk < 4; ++kk)
    af[kk] = *(const short8v*)&as_[ln15][kk * 32 + g * 8];

  f32x4 acc[8];
#pragma unroll
  for (int cb = 0; cb < 8; ++cb) acc[cb] = (f32x4){0.f, 0.f, 0.f, 0.f};

#pragma unroll
  for (int kk = 0; kk < 4; ++kk) {
#pragma unroll
    for (int cb = 0; cb < 8; ++cb) {
      const short8v bfr =
          *(const short8v*)(wto + (cb * 16 + ln15) * 128 + kk * 32 + g * 8);
      acc[cb] = __builtin_amdgcn_mfma_f32_16x16x32_bf16(af[kk], bfr, acc[cb], 0, 0, 0);
    }
  }

#pragma unroll
  for (int cb = 0; cb < 8; ++cb) {
    const int col = cb * 16 + ln15;
    const float bov = bo[col];
#pragma unroll
    for (int r = 0; r < 4; ++r) {
      const long row = rowBase + g * 4 + r;
      acc[cb][r] += bov + x[row * 128 + col];
    }
  }

  float s1[4], s2[4];
#pragma unroll
  for (int r = 0; r < 4; ++r) {
    s1[r] = 0.f; s2[r] = 0.f;
#pragma unroll
    for (int cb = 0; cb < 8; ++cb) {
      s1[r] += acc[cb][r];
      s2[r] = fmaf(acc[cb][r], acc[cb][r], s2[r]);
    }
  }
#pragma unroll
  for (int m = 1; m < 16; m <<= 1) {
#pragma unroll
    for (int r = 0; r < 4; ++r) {
      s1[r] += __shfl_xor(s1[r], m);
      s2[r] += __shfl_xor(s2[r], m);
    }
  }
  float mu[4], inv[4];
#pragma unroll
  for (int r = 0; r < 4; ++r) {
    mu[r] = s1[r] * (1.f / 128.f);
    const float var = s2[r] * (1.f / 128.f) - mu[r] * mu[r];
    inv[r] = rsqrtf(var + 1e-5f);
  }

#pragma unroll
  for (int cb = 0; cb < 8; ++cb) {
    const int col = cb * 16 + ln15;
    const float gv = lng[col], bv_ = lnb[col];
#pragma unroll
    for (int r = 0; r < 4; ++r) {
      const long row = rowBase + g * 4 + r;
      out[row * 128 + col] = (acc[cb][r] - mu[r]) * inv[r] * gv + bv_;
    }
  }
}

// ---------------------------------------------------------------------------
extern "C" void kernel_launch(void* const* d_in, const int* in_sizes, int n_in,
                              void* d_out, int out_size, void* d_ws, size_t ws_size,
                              hipStream_t stream) {
  const float* x   = (const float*)d_in[0];
  const int*   ei  = (const int*)d_in[1];
  const float* ea  = (const float*)d_in[2];
  const float* Wq  = (const float*)d_in[3];
  const float* bq  = (const float*)d_in[4];
  const float* Wk  = (const float*)d_in[5];
  const float* bk  = (const float*)d_in[6];
  const float* Wv  = (const float*)d_in[7];
  const float* bv  = (const float*)d_in[8];
  const float* Wf  = (const float*)d_in[9];
  const float* bf  = (const float*)d_in[10];
  const float* Wo  = (const float*)d_in[11];
  const float* bo  = (const float*)d_in[12];
  const float* lng = (const float*)d_in[13];
  const float* lnb = (const float*)d_in[14];
  float* out = (float*)d_out;

  const size_t NQ = (size_t)B_ * N_ * HID_;  // 5,120,000

  char* base = (char*)d_ws;
  size_t off = 0;
  unsigned short* Qb = (unsigned short*)(base + off); off += NQ * 2;   // 10.24MB
  float* agg  = (float*)(base + off); off += NQ * 4;                   // 20.48MB
  unsigned char* kv8 = (unsigned char*)(base + off);
  off += (size_t)B_ * N_ * 256;                                        // 10.24MB
  unsigned char* film8 = (unsigned char*)(base + off);
  off += (size_t)E_ * 256;                                             // 40.96MB
  short* wt   = (short*)(base + off); off += 4 * 16384 * 2;            // 128KB
  int*  cnt    = (int*)(base + off); off += N_ * 4;
  int*  rowptr = (int*)(base + off); off += (N_ + 1) * 4;
  int*  fill   = (int*)(base + off); off += N_ * 4;
  int*  esrc   = (int*)(base + off); off += E_ * 4;
  int*  eord   = (int*)(base + off); off += E_ * 4;

  hipMemsetAsync(cnt, 0, N_ * sizeof(int), stream);

  wt_prep<<<256, 256, 0, stream>>>(Wq, Wk, Wv, Wo, wt);
  phase1<<<QKV_BLKS + FILM_BLKS + HIST_BLKS, 256, 0, stream>>>(
      x, wt, bq, bk, bv, Qb, kv8, ea, Wf, bf, film8, ei, cnt);
  csr_scan<<<1, 1024, 0, stream>>>(cnt, rowptr, fill);
  csr_scatter<<<(E_ + 255) / 256, 256, 0, stream>>>(ei, fill, esrc, eord);
  fused_attn<<<PGRID, 256, 0, stream>>>(rowptr, esrc, eord, film8, Qb, kv8, agg);
  out_ln_mfma<<<(B_ * N_) / 16, 64, 0, stream>>>(agg, wt + 3 * 16384, bo, x, lng, lnb, out);
}

// Round 23
// 158.818 us; speedup vs baseline: 1.0920x; 1.0920x over previous
//
#include <hip/hip_runtime.h>
#include <hip/hip_bf16.h>

#define B_ 4
#define N_ 10000
#define E_ 160000
#define D_ 128
#define H_ 4
#define HID_ 128
#define DK_ 32
#define DE_ 16
#define PGRID 2048
#define FILM_BLKS 2048
#define QKV_BLKS 625
#define HIST_BLKS 625   // ceil(E/256)

typedef __attribute__((ext_vector_type(8))) short short8v;
typedef __attribute__((ext_vector_type(4))) short short4v;
typedef __attribute__((ext_vector_type(4))) float f32x4;
typedef __attribute__((ext_vector_type(2))) float f32x2;

// fp32 -> bf16 bits, round-to-nearest-even
__device__ __forceinline__ short bfb(float f) {
  union { float f; unsigned u; } c; c.f = f;
  unsigned u = c.u + 0x7FFFu + ((c.u >> 16) & 1u);
  return (short)(u >> 16);
}
// bf16 bits -> fp32
__device__ __forceinline__ float b2f(unsigned short u) {
  union { unsigned u; float f; } c; c.u = ((unsigned)u) << 16;
  return c.f;
}

// fp32 -> fp8 e4m3 (OCP on gfx950)
__device__ __forceinline__ unsigned char f2fp8(float f) {
  int r = __builtin_amdgcn_cvt_pk_fp8_f32(f, f, 0, false);
  return (unsigned char)(r & 0xff);
}
// dword of 4 fp8 -> 2+2 fp32
__device__ __forceinline__ f32x2 fp8lo(unsigned u) {
  return __builtin_amdgcn_cvt_pk_f32_fp8((int)u, false);
}
__device__ __forceinline__ f32x2 fp8hi(unsigned u) {
  return __builtin_amdgcn_cvt_pk_f32_fp8((int)u, true);
}

// ---------------------------------------------------------------------------
// P0: W^T bf16 prep. wt[m][n][k] = bf16(W_m[k*128+n]),  m: 0=q 1=k 2=v 3=o
// ---------------------------------------------------------------------------
__global__ __launch_bounds__(256) void wt_prep(
    const float* __restrict__ Wq, const float* __restrict__ Wk,
    const float* __restrict__ Wv, const float* __restrict__ Wo,
    short* __restrict__ wt) {
  const float* Ws[4] = {Wq, Wk, Wv, Wo};
  const int i = blockIdx.x * 256 + threadIdx.x;   // 0..65535
  const int m = i >> 14;
  const int k = (i >> 7) & 127;
  const int n = i & 127;
  wt[(size_t)m * 16384 + n * 128 + k] = bfb(Ws[m][k * 128 + n]);
}

// ---------------------------------------------------------------------------
// PHASE 1: co-scheduled film + qkv + hist. FILM FIRST (longest pole) with
// its full solo grid (2048 blocks); qkv/hist fill residual slots and retire
// early. Film's dependent FMA chain split 16 -> 2x8 for ILP.
// ---------------------------------------------------------------------------
__global__ __launch_bounds__(256) void phase1(
    const float* __restrict__ x, const short* __restrict__ wt,
    const float* __restrict__ bq, const float* __restrict__ bk,
    const float* __restrict__ bv,
    unsigned short* __restrict__ Qb, unsigned char* __restrict__ kv8,
    const float* __restrict__ ea, const float* __restrict__ Wf,
    const float* __restrict__ bf, unsigned char* __restrict__ film8,
    const int* __restrict__ ei, int* __restrict__ cnt) {
  const int blk = blockIdx.x;

  if (blk < FILM_BLKS) {
    // ---------------- FiLM fp8 precompute (full-parallelism) ----------------
    const int lane = threadIdx.x & 63;
    const int wave = threadIdx.x >> 6;
    const int c0 = lane * 4;

    float4 w[16];
#pragma unroll
    for (int j = 0; j < 16; ++j) w[j] = *(const float4*)(Wf + j * 256 + c0);
    const float4 bias = *(const float4*)(bf + c0);

    for (int i = blk * 4 + wave; i < E_; i += FILM_BLKS * 4) {
      const float* ep = ea + (size_t)i * 16;
      const float4 a0 = *(const float4*)ep;
      const float4 a1 = *(const float4*)(ep + 4);
      const float4 a2 = *(const float4*)(ep + 8);
      const float4 a3 = *(const float4*)(ep + 12);
      const float ev[16] = {a0.x,a0.y,a0.z,a0.w, a1.x,a1.y,a1.z,a1.w,
                            a2.x,a2.y,a2.z,a2.w, a3.x,a3.y,a3.z,a3.w};
      // two independent 8-deep chains per output (ILP)
      float ox0 = bias.x, oy0 = bias.y, oz0 = bias.z, ow0 = bias.w;
      float ox1 = 0.f, oy1 = 0.f, oz1 = 0.f, ow1 = 0.f;
#pragma unroll
      for (int j = 0; j < 8; ++j) {
        ox0 = fmaf(ev[j], w[j].x, ox0);
        oy0 = fmaf(ev[j], w[j].y, oy0);
        oz0 = fmaf(ev[j], w[j].z, oz0);
        ow0 = fmaf(ev[j], w[j].w, ow0);
        ox1 = fmaf(ev[8 + j], w[8 + j].x, ox1);
        oy1 = fmaf(ev[8 + j], w[8 + j].y, oy1);
        oz1 = fmaf(ev[8 + j], w[8 + j].z, oz1);
        ow1 = fmaf(ev[8 + j], w[8 + j].w, ow1);
      }
      int r = __builtin_amdgcn_cvt_pk_fp8_f32(ox0 + ox1, oy0 + oy1, 0, false);
      r = __builtin_amdgcn_cvt_pk_fp8_f32(oz0 + oz1, ow0 + ow1, r, true);
      ((int*)(film8 + (size_t)i * 256))[lane] = r;
    }
  } else if (blk < FILM_BLKS + QKV_BLKS) {
    // ---------------- QKV (4 wave-tiles per block) ----------------
    __shared__ short xs[4][16][136];
    const int qb   = blk - FILM_BLKS;
    const int wave = threadIdx.x >> 6;
    const int lane = threadIdx.x & 63;
    const int ln15 = lane & 15;
    const int g    = lane >> 4;
    const long rowBase = ((long)qb * 4 + wave) * 16;

    for (int i = lane; i < 16 * 32; i += 64) {
      const int r  = i >> 5;
      const int c4 = (i & 31) * 4;
      const float4 v = *(const float4*)(x + (rowBase + r) * 128 + c4);
      short4v sv; sv.x = bfb(v.x); sv.y = bfb(v.y); sv.z = bfb(v.z); sv.w = bfb(v.w);
      *(short4v*)&xs[wave][r][c4] = sv;
    }
    __syncthreads();   // branch is uniform per block -> safe

    short8v af[4];
#pragma unroll
    for (int kk = 0; kk < 4; ++kk)
      af[kk] = *(const short8v*)&xs[wave][ln15][kk * 32 + g * 8];

    const float* bs[3] = {bq, bk, bv};

    int bbv[4], nnv[4];
#pragma unroll
    for (int r = 0; r < 4; ++r) {
      const long row = rowBase + g * 4 + r;
      bbv[r] = (int)(row / N_);
      nnv[r] = (int)(row - (long)bbv[r] * N_);
    }

#pragma unroll
    for (int m = 0; m < 3; ++m) {
      const short* Wt = wt + (size_t)m * 16384;
      f32x4 acc[8];
#pragma unroll
      for (int cb = 0; cb < 8; ++cb) acc[cb] = (f32x4){0.f, 0.f, 0.f, 0.f};

#pragma unroll
      for (int kk = 0; kk < 4; ++kk) {
#pragma unroll
        for (int cb = 0; cb < 8; ++cb) {
          const short8v bfr =
              *(const short8v*)(Wt + (cb * 16 + ln15) * 128 + kk * 32 + g * 8);
          acc[cb] = __builtin_amdgcn_mfma_f32_16x16x32_bf16(af[kk], bfr, acc[cb], 0, 0, 0);
        }
      }

      const float* bias = bs[m];
#pragma unroll
      for (int cb = 0; cb < 8; ++cb) {
        const int col = cb * 16 + ln15;
        const float bv_ = bias[col];
#pragma unroll
        for (int r = 0; r < 4; ++r) {
          const float val = acc[cb][r] + bv_;
          if (m == 0) {
            const long row = rowBase + g * 4 + r;
            Qb[row * 128 + col] = (unsigned short)bfb(val);
          } else {
            kv8[(((size_t)nnv[r] * 4 + bbv[r]) << 8) + (m - 1) * 128 + col] = f2fp8(val);
          }
        }
      }
    }
  } else {
    // ---------------- dst histogram ----------------
    const int e = (blk - FILM_BLKS - QKV_BLKS) * 256 + threadIdx.x;
    if (e < E_) atomicAdd(&cnt[ei[E_ + e]], 1);
  }
}

// ---------------------------------------------------------------------------
// CSR scan
// ---------------------------------------------------------------------------
__global__ __launch_bounds__(1024) void csr_scan(const int* __restrict__ cnt,
                                                 int* __restrict__ rowptr,
                                                 int* __restrict__ fill) {
  __shared__ int part[1024];
  const int t = threadIdx.x;
  int local[10];
  int sum = 0;
#pragma unroll
  for (int i = 0; i < 10; ++i) {
    const int idx = t * 10 + i;
    local[i] = sum;
    sum += (idx < N_) ? cnt[idx] : 0;
  }
  part[t] = sum;
  __syncthreads();
  for (int off = 1; off < 1024; off <<= 1) {
    const int v = (t >= off) ? part[t - off] : 0;
    __syncthreads();
    part[t] += v;
    __syncthreads();
  }
  const int excl = (t == 0) ? 0 : part[t - 1];
#pragma unroll
  for (int i = 0; i < 10; ++i) {
    const int idx = t * 10 + i;
    if (idx <= N_) {
      const int o = excl + local[i];
      rowptr[idx] = o;
      if (idx < N_) fill[idx] = o;
    }
  }
}

// scatter: CSR-ordered src + original-edge-id map (no edge_attr copy)
__global__ __launch_bounds__(256) void csr_scatter(
    const int* __restrict__ ei, int* __restrict__ fill,
    int* __restrict__ esrc, int* __restrict__ eord) {
  const int e = blockIdx.x * 256 + threadIdx.x;
  if (e < E_) {
    const int dst = ei[E_ + e];
    const int pos = atomicAdd(&fill[dst], 1);
    esrc[pos] = ei[e];
    eord[pos] = e;
  }
}

// ---------------------------------------------------------------------------
// K2: fused logits + softmax + aggregation — ZERO shuffles in the edge loop.
// Persistent: PGRID blocks x 4 waves; wave = node (grid-stride).
// lane = e2*32 + dh*16 + b*4 + h.  film gathered via eord (original edge id).
// ---------------------------------------------------------------------------
__global__ __launch_bounds__(256) void fused_attn(
    const int* __restrict__ rowptr, const int* __restrict__ esrc,
    const int* __restrict__ eord, const unsigned char* __restrict__ film8,
    const unsigned short* __restrict__ Qb,
    const unsigned char* __restrict__ kv8, float* __restrict__ agg) {
  const int wave = threadIdx.x >> 6;
  const int lane = threadIdx.x & 63;
  const int e2 = lane >> 5;
  const int dh = (lane >> 4) & 1;
  const int b  = (lane >> 2) & 3;
  const int h  = lane & 3;
  const int col0 = h * 32 + dh * 16;

  for (int node = blockIdx.x * 4 + wave; node < N_; node += PGRID * 4) {
    const int beg = rowptr[node], end = rowptr[node + 1];

    float q[16];
    {
      const unsigned short* qp = Qb + ((size_t)b * N_ + node) * 128 + col0;
      const short8v t0 = *(const short8v*)qp;
      const short8v t1 = *(const short8v*)(qp + 8);
#pragma unroll
      for (int j = 0; j < 8; ++j) {
        q[j]     = b2f((unsigned short)t0[j]);
        q[8 + j] = b2f((unsigned short)t1[j]);
      }
    }
    float acc[16];
#pragma unroll
    for (int d = 0; d < 16; ++d) acc[d] = 0.f;
    float se = 0.f;

    for (int i0 = beg; i0 < end; i0 += 2) {
      const int ii = i0 + e2;
      const bool valid = ii < end;
      const int ic = valid ? ii : i0;
      const int src = esrc[ic];
      const int de  = eord[ic];
      const unsigned char* kp = kv8 + ((((size_t)src << 2) + b) << 8) + col0;
      const unsigned char* fp = film8 + (size_t)de * 256 + col0;
      const uint4 kw = *(const uint4*)kp;
      const uint4 vw = *(const uint4*)(kp + 128);
      const uint4 gw = *(const uint4*)fp;
      const uint4 tw = *(const uint4*)(fp + 128);
      const unsigned ks[4] = {kw.x, kw.y, kw.z, kw.w};
      const unsigned vs[4] = {vw.x, vw.y, vw.z, vw.w};
      const unsigned gs[4] = {gw.x, gw.y, gw.z, gw.w};
      const unsigned ts[4] = {tw.x, tw.y, tw.z, tw.w};

      float pacc[4] = {0.f, 0.f, 0.f, 0.f};
#pragma unroll
      for (int w = 0; w < 4; ++w) {
        const f32x2 k0 = fp8lo(ks[w]), k1 = fp8hi(ks[w]);
        const f32x2 g0 = fp8lo(gs[w]), g1 = fp8hi(gs[w]);
        const f32x2 t0 = fp8lo(ts[w]), t1 = fp8hi(ts[w]);
        float km;
        km = k0.x + fmaf(k0.x, g0.x, t0.x); pacc[w] = fmaf(q[4*w+0], km, pacc[w]);
        km = k0.y + fmaf(k0.y, g0.y, t0.y); pacc[w] = fmaf(q[4*w+1], km, pacc[w]);
        km = k1.x + fmaf(k1.x, g1.x, t1.x); pacc[w] = fmaf(q[4*w+2], km, pacc[w]);
        km = k1.y + fmaf(k1.y, g1.y, t1.y); pacc[w] = fmaf(q[4*w+3], km, pacc[w]);
      }
      float pl = (pacc[0] + pacc[1]) + (pacc[2] + pacc[3]);
      pl += __shfl_xor(pl, 16);   // join dh halves -> full 32-dim logit

      float ex = __expf(pl * 0.17677669529663687f);  // 1/sqrt(32)
      ex = valid ? ex : 0.f;
      se += ex;
#pragma unroll
      for (int w = 0; w < 4; ++w) {
        const f32x2 v0 = fp8lo(vs[w]), v1 = fp8hi(vs[w]);
        acc[4*w+0] = fmaf(ex, v0.x, acc[4*w+0]);
        acc[4*w+1] = fmaf(ex, v0.y, acc[4*w+1]);
        acc[4*w+2] = fmaf(ex, v1.x, acc[4*w+2]);
        acc[4*w+3] = fmaf(ex, v1.y, acc[4*w+3]);
      }
    }

    // join the two e2 slots
#pragma unroll
    for (int d = 0; d < 16; ++d) acc[d] += __shfl_xor(acc[d], 32);
    se += __shfl_xor(se, 32);

    if (e2 == 0) {
      const float inv = (end > beg) ? 1.f / se : 0.f;
      float* ap = agg + ((size_t)b * N_ + node) * 128 + col0;
#pragma unroll
      for (int c = 0; c < 4; ++c) {
        float4 o;
        o.x = acc[c*4+0] * inv; o.y = acc[c*4+1] * inv;
        o.z = acc[c*4+2] * inv; o.w = acc[c*4+3] * inv;
        *(float4*)(ap + c * 4) = o;
      }
    }
  }
}

// ---------------------------------------------------------------------------
// K4: y = agg @ Wo + bo (MFMA); h = x + y; LayerNorm(h) -> out
// ONE WAVE per block, 16 rows/block, grid 2500.
// ---------------------------------------------------------------------------
__global__ __launch_bounds__(64) void out_ln_mfma(
    const float* __restrict__ agg, const short* __restrict__ wto,
    const float* __restrict__ bo, const float* __restrict__ x,
    const float* __restrict__ lng, const float* __restrict__ lnb,
    float* __restrict__ out) {
  __shared__ short as_[16][136];
  const int lane = threadIdx.x;
  const int ln15 = lane & 15;
  const int g    = lane >> 4;
  const long rowBase = (long)blockIdx.x * 16;

  for (int i = lane; i < 16 * 32; i += 64) {
    const int r  = i >> 5;
    const int c4 = (i & 31) * 4;
    const float4 v = *(const float4*)(agg + (rowBase + r) * 128 + c4);
    short4v sv; sv.x = bfb(v.x); sv.y = bfb(v.y); sv.z = bfb(v.z); sv.w = bfb(v.w);
    *(short4v*)&as_[r][c4] = sv;
  }
  __syncthreads();

  short8v af[4];
#pragma unroll
  for (int kk = 0; kk < 4; ++kk)
    af[kk] = *(const short8v*)&as_[ln15][kk * 32 + g * 8];

  f32x4 acc[8];
#pragma unroll
  for (int cb = 0; cb < 8; ++cb) acc[cb] = (f32x4){0.f, 0.f, 0.f, 0.f};

#pragma unroll
  for (int kk = 0; kk < 4; ++kk) {
#pragma unroll
    for (int cb = 0; cb < 8; ++cb) {
      const short8v bfr =
          *(const short8v*)(wto + (cb * 16 + ln15) * 128 + kk * 32 + g * 8);
      acc[cb] = __builtin_amdgcn_mfma_f32_16x16x32_bf16(af[kk], bfr, acc[cb], 0, 0, 0);
    }
  }

#pragma unroll
  for (int cb = 0; cb < 8; ++cb) {
    const int col = cb * 16 + ln15;
    const float bov = bo[col];
#pragma unroll
    for (int r = 0; r < 4; ++r) {
      const long row = rowBase + g * 4 + r;
      acc[cb][r] += bov + x[row * 128 + col];
    }
  }

  float s1[4], s2[4];
#pragma unroll
  for (int r = 0; r < 4; ++r) {
    s1[r] = 0.f; s2[r] = 0.f;
#pragma unroll
    for (int cb = 0; cb < 8; ++cb) {
      s1[r] += acc[cb][r];
      s2[r] = fmaf(acc[cb][r], acc[cb][r], s2[r]);
    }
  }
#pragma unroll
  for (int m = 1; m < 16; m <<= 1) {
#pragma unroll
    for (int r = 0; r < 4; ++r) {
      s1[r] += __shfl_xor(s1[r], m);
      s2[r] += __shfl_xor(s2[r], m);
    }
  }
  float mu[4], inv[4];
#pragma unroll
  for (int r = 0; r < 4; ++r) {
    mu[r] = s1[r] * (1.f / 128.f);
    const float var = s2[r] * (1.f / 128.f) - mu[r] * mu[r];
    inv[r] = rsqrtf(var + 1e-5f);
  }

#pragma unroll
  for (int cb = 0; cb < 8; ++cb) {
    const int col = cb * 16 + ln15;
    const float gv = lng[col], bv_ = lnb[col];
#pragma unroll
    for (int r = 0; r < 4; ++r) {
      const long row = rowBase + g * 4 + r;
      out[row * 128 + col] = (acc[cb][r] - mu[r]) * inv[r] * gv + bv_;
    }
  }
}

// ---------------------------------------------------------------------------
extern "C" void kernel_launch(void* const* d_in, const int* in_sizes, int n_in,
                              void* d_out, int out_size, void* d_ws, size_t ws_size,
                              hipStream_t stream) {
  const float* x   = (const float*)d_in[0];
  const int*   ei  = (const int*)d_in[1];
  const float* ea  = (const float*)d_in[2];
  const float* Wq  = (const float*)d_in[3];
  const float* bq  = (const float*)d_in[4];
  const float* Wk  = (const float*)d_in[5];
  const float* bk  = (const float*)d_in[6];
  const float* Wv  = (const float*)d_in[7];
  const float* bv  = (const float*)d_in[8];
  const float* Wf  = (const float*)d_in[9];
  const float* bf  = (const float*)d_in[10];
  const float* Wo  = (const float*)d_in[11];
  const float* bo  = (const float*)d_in[12];
  const float* lng = (const float*)d_in[13];
  const float* lnb = (const float*)d_in[14];
  float* out = (float*)d_out;

  const size_t NQ = (size_t)B_ * N_ * HID_;  // 5,120,000

  char* base = (char*)d_ws;
  size_t off = 0;
  unsigned short* Qb = (unsigned short*)(base + off); off += NQ * 2;   // 10.24MB
  float* agg  = (float*)(base + off); off += NQ * 4;                   // 20.48MB
  unsigned char* kv8 = (unsigned char*)(base + off);
  off += (size_t)B_ * N_ * 256;                                        // 10.24MB
  unsigned char* film8 = (unsigned char*)(base + off);
  off += (size_t)E_ * 256;                                             // 40.96MB
  short* wt   = (short*)(base + off); off += 4 * 16384 * 2;            // 128KB
  int*  cnt    = (int*)(base + off); off += N_ * 4;
  int*  rowptr = (int*)(base + off); off += (N_ + 1) * 4;
  int*  fill   = (int*)(base + off); off += N_ * 4;
  int*  esrc   = (int*)(base + off); off += E_ * 4;
  int*  eord   = (int*)(base + off); off += E_ * 4;

  hipMemsetAsync(cnt, 0, N_ * sizeof(int), stream);

  wt_prep<<<256, 256, 0, stream>>>(Wq, Wk, Wv, Wo, wt);
  phase1<<<FILM_BLKS + QKV_BLKS + HIST_BLKS, 256, 0, stream>>>(
      x, wt, bq, bk, bv, Qb, kv8, ea, Wf, bf, film8, ei, cnt);
  csr_scan<<<1, 1024, 0, stream>>>(cnt, rowptr, fill);
  csr_scatter<<<(E_ + 255) / 256, 256, 0, stream>>>(ei, fill, esrc, eord);
  fused_attn<<<PGRID, 256, 0, stream>>>(rowptr, esrc, eord, film8, Qb, kv8, agg);
  out_ln_mfma<<<(B_ * N_) / 16, 64, 0, stream>>>(agg, wt + 3 * 16384, bo, x, lng, lnb, out);
}